// Round 6
// baseline (1258.767 us; speedup 1.0000x reference)
//
#include <hip/hip_runtime.h>

// ---------------------------------------------------------------------------
// minerva_35124242547419 — R6: OUTPUT IS FLOAT32 (R5's err decomposed exactly
// as f32-read of two packed bf16 halves). Inputs f32 (proven R3->R4).
// Pipeline (audited):
//   f  = l2norm(features @ g_w.T)   [4096,256]  (bf16 MFMA, f32 staged->bf16)
//   ef = l2norm(ex_features @ g_w.T)[16384,256]
//   u  = (f @ ef.T)^3               [4096,16384] bf16 materialized
//   t  = (u @ l1norm(ex_classes)) / rowsum|u|   [4096,28]  (r from SAME u)
//   echo = t @ class_reps ; neg_dists = -cdist ; BCE loss (f32 out)
// ---------------------------------------------------------------------------

typedef __bf16 bf16x8 __attribute__((ext_vector_type(8)));
typedef __bf16 bf16x4 __attribute__((ext_vector_type(4)));
typedef float  f32x4  __attribute__((ext_vector_type(4)));

__device__ __forceinline__ f32x4 f4zero() { f32x4 z = {0.f, 0.f, 0.f, 0.f}; return z; }

__device__ __forceinline__ f32x4 mfma16(bf16x8 a, bf16x8 b, f32x4 c) {
  return __builtin_amdgcn_mfma_f32_16x16x32_bf16(a, b, c, 0, 0, 0);
}

// 8 consecutive f32 -> bf16x8
__device__ __forceinline__ bf16x8 load8f(const float* p) {
  f32x4 a = *(const f32x4*)p;
  f32x4 b = *(const f32x4*)(p + 4);
  bf16x8 r;
  r[0] = (__bf16)a[0]; r[1] = (__bf16)a[1]; r[2] = (__bf16)a[2]; r[3] = (__bf16)a[3];
  r[4] = (__bf16)b[0]; r[5] = (__bf16)b[1]; r[6] = (__bf16)b[2]; r[7] = (__bf16)b[3];
  return r;
}

__global__ void zero_f32(float* __restrict__ p, int n) {
  for (int i = blockIdx.x * 256 + threadIdx.x; i < n; i += gridDim.x * 256) p[i] = 0.f;
}

__global__ void fill_sentinel(float* __restrict__ out, int n) {
  for (int i = blockIdx.x * 256 + threadIdx.x; i < n; i += gridDim.x * 256) out[i] = -1.0f;
}

// ---------------------------------------------------------------------------
// P = l2norm_rows(X @ W^T), X [M,1024] f32, W [256,1024] f32 -> P bf16.
// Block: 128 rows x 256 cols (full N). 4 waves 2x2.
// blocks 0..127 -> ex_features, 128..159 -> features.
// ---------------------------------------------------------------------------
__global__ __launch_bounds__(256, 1)
void proj_l2norm(const float* __restrict__ Xa, const float* __restrict__ Xb,
                 const float* __restrict__ W,
                 __bf16* __restrict__ Pa, __bf16* __restrict__ Pb) {
  __shared__ __align__(16) __bf16 Xs[128 * 40];
  __shared__ __align__(16) __bf16 Ws[256 * 40];
  __shared__ float nrm[256];
  __shared__ float invn[128];

  const int tid = threadIdx.x;
  const int w = tid >> 6, lane = tid & 63;
  const int quad = lane >> 4, l15 = lane & 15;
  const int wy = w >> 1, wx = w & 1;

  const float* X;
  __bf16* P;
  int row0;
  if (blockIdx.x < 128) { X = Xa; P = Pa; row0 = blockIdx.x * 128; }
  else                  { X = Xb; P = Pb; row0 = (blockIdx.x - 128) * 128; }

  f32x4 acc[4][8];
#pragma unroll
  for (int i = 0; i < 4; i++)
#pragma unroll
    for (int j = 0; j < 8; j++) acc[i][j] = f4zero();

  for (int ks = 0; ks < 32; ks++) {
    __syncthreads();
#pragma unroll
    for (int rep = 0; rep < 2; rep++) {
      int idx = rep * 256 + tid;
      int row = idx >> 2, c8 = idx & 3;
      *(bf16x8*)(Xs + row * 40 + c8 * 8) =
          load8f(X + (size_t)(row0 + row) * 1024 + ks * 32 + c8 * 8);
    }
#pragma unroll
    for (int rep = 0; rep < 4; rep++) {
      int idx = rep * 256 + tid;
      int row = idx >> 2, c8 = idx & 3;
      *(bf16x8*)(Ws + row * 40 + c8 * 8) =
          load8f(W + (size_t)row * 1024 + ks * 32 + c8 * 8);
    }
    __syncthreads();
    bf16x8 af[4], bfr[8];
#pragma unroll
    for (int mb = 0; mb < 4; mb++)
      af[mb] = *(bf16x8*)(Xs + (wy * 64 + mb * 16 + l15) * 40 + quad * 8);
#pragma unroll
    for (int nb = 0; nb < 8; nb++)
      bfr[nb] = *(bf16x8*)(Ws + (wx * 128 + nb * 16 + l15) * 40 + quad * 8);
#pragma unroll
    for (int mb = 0; mb < 4; mb++)
#pragma unroll
      for (int nb = 0; nb < 8; nb++)
        acc[mb][nb] = mfma16(af[mb], bfr[nb], acc[mb][nb]);
  }

  float part[4][4];
#pragma unroll
  for (int mb = 0; mb < 4; mb++)
#pragma unroll
    for (int r = 0; r < 4; r++) {
      float s = 0.f;
#pragma unroll
      for (int nb = 0; nb < 8; nb++) { float v = acc[mb][nb][r]; s += v * v; }
      part[mb][r] = s;
    }
#pragma unroll
  for (int m = 1; m < 16; m <<= 1)
#pragma unroll
    for (int mb = 0; mb < 4; mb++)
#pragma unroll
      for (int r = 0; r < 4; r++) part[mb][r] += __shfl_xor(part[mb][r], m, 64);

  if (l15 == 0) {
#pragma unroll
    for (int mb = 0; mb < 4; mb++)
#pragma unroll
      for (int r = 0; r < 4; r++)
        nrm[wx * 128 + wy * 64 + mb * 16 + quad * 4 + r] = part[mb][r];
  }
  __syncthreads();
  if (tid < 128) {
    float s = nrm[tid] + nrm[128 + tid];
    invn[tid] = 1.0f / fmaxf(sqrtf(s), 1e-12f);
  }
  __syncthreads();
#pragma unroll
  for (int mb = 0; mb < 4; mb++)
#pragma unroll
    for (int nb = 0; nb < 8; nb++)
#pragma unroll
      for (int r = 0; r < 4; r++) {
        int row = wy * 64 + mb * 16 + quad * 4 + r;
        int col = wx * 128 + nb * 16 + l15;
        P[(size_t)(row0 + row) * 256 + col] = (__bf16)(acc[mb][nb][r] * invn[row]);
      }
}

// ---------------------------------------------------------------------------
// vt[e][j] = l1norm_row(ex_classes)[e][j], f32 [16384][28].
// ---------------------------------------------------------------------------
__global__ void build_vt_f32(const float* __restrict__ exc, float* __restrict__ vt) {
  int e = blockIdx.x * 256 + threadIdx.x;
  float m[28];
  float s = 0.f;
#pragma unroll
  for (int j = 0; j < 28; j++) {
    m[j] = exc[(size_t)e * 28 + j];
    s += fabsf(m[j]);
  }
  float inv = 1.0f / fmaxf(s, 1e-12f);
#pragma unroll
  for (int j = 0; j < 28; j++) vt[(size_t)e * 28 + j] = m[j] * inv;
}

// ---------------------------------------------------------------------------
// u[q][e] = (f[q].ef[e])^3 bf16, materialized.
// Block: 128e x 128q, 4 waves 2x2. grid 4096 = 128 etiles x 32 qtiles.
// ---------------------------------------------------------------------------
__global__ __launch_bounds__(256, 1)
void sim_s3(const __bf16* __restrict__ fn, const __bf16* __restrict__ efn,
            __bf16* __restrict__ u) {
  __shared__ __align__(16) __bf16 Es[128 * 40];
  __shared__ __align__(16) __bf16 Fs[128 * 40];

  const int tid = threadIdx.x;
  const int w = tid >> 6, lane = tid & 63;
  const int quad = lane >> 4, l15 = lane & 15;
  const int wy = w >> 1, wx = w & 1;
  const int e0 = (blockIdx.x & 127) * 128;
  const int q0 = (blockIdx.x >> 7) * 128;

  f32x4 acc[4][4];
#pragma unroll
  for (int a = 0; a < 4; a++)
#pragma unroll
    for (int b = 0; b < 4; b++) acc[a][b] = f4zero();

  for (int ks = 0; ks < 8; ks++) {
    __syncthreads();
#pragma unroll
    for (int rep = 0; rep < 2; rep++) {
      int idx = rep * 256 + tid;
      int row = idx >> 2, c8 = idx & 3;
      *(bf16x8*)(Es + row * 40 + c8 * 8) =
          *(const bf16x8*)(efn + (size_t)(e0 + row) * 256 + ks * 32 + c8 * 8);
      *(bf16x8*)(Fs + row * 40 + c8 * 8) =
          *(const bf16x8*)(fn + (size_t)(q0 + row) * 256 + ks * 32 + c8 * 8);
    }
    __syncthreads();
    bf16x8 af[4], bfr[4];
#pragma unroll
    for (int mb = 0; mb < 4; mb++)
      af[mb] = *(bf16x8*)(Es + (wy * 64 + mb * 16 + l15) * 40 + quad * 8);
#pragma unroll
    for (int nb = 0; nb < 4; nb++)
      bfr[nb] = *(bf16x8*)(Fs + (wx * 64 + nb * 16 + l15) * 40 + quad * 8);
#pragma unroll
    for (int mb = 0; mb < 4; mb++)
#pragma unroll
      for (int nb = 0; nb < 4; nb++)
        acc[mb][nb] = mfma16(af[mb], bfr[nb], acc[mb][nb]);
  }

#pragma unroll
  for (int mb = 0; mb < 4; mb++) {
    const int e_loc = wy * 64 + mb * 16 + quad * 4;
#pragma unroll
    for (int nb = 0; nb < 4; nb++) {
      const int q = q0 + wx * 64 + nb * 16 + l15;
      bf16x4 pk;
#pragma unroll
      for (int r = 0; r < 4; r++) {
        float s = acc[mb][nb][r];
        pk[r] = (__bf16)(s * s * s);
      }
      *(bf16x4*)(u + (size_t)q * 16384 + e0 + e_loc) = pk;
    }
  }
}

// ---------------------------------------------------------------------------
// tT[q][c'] += sum_e u[q][e]*vt[e][c'];  r_acc[q] += sum_e |u[q][e]|.
// grid 1024 = 64 qgroups x 16 echunks; block 256 = 64 q x 4 esub.
// ---------------------------------------------------------------------------
__global__ __launch_bounds__(256, 1)
void pv_accum(const __bf16* __restrict__ u, const float* __restrict__ vt,
              float* __restrict__ tT, float* __restrict__ r_acc) {
  const int tid = threadIdx.x;
  const int qg = blockIdx.x >> 4, ec = blockIdx.x & 15;
  const int q_l = tid >> 2, esub = tid & 3;
  const int q = qg * 64 + q_l;

  f32x4 acc4[7];
#pragma unroll
  for (int c = 0; c < 7; c++) acc4[c] = f4zero();
  float rp = 0.f;

  for (int i = 0; i < 32; i++) {
    const int e = ec * 1024 + esub * 256 + i * 8;
    bf16x8 uv = *(const bf16x8*)(u + (size_t)q * 16384 + e);
#pragma unroll
    for (int j = 0; j < 8; j++) {
      float uj = (float)uv[j];
      rp += fabsf(uj);
      const f32x4* vrow = (const f32x4*)(vt + (size_t)(e + j) * 28);
#pragma unroll
      for (int c = 0; c < 7; c++) acc4[c] += uj * vrow[c];
    }
  }
#pragma unroll
  for (int m = 1; m < 4; m <<= 1) {
    rp += __shfl_xor(rp, m, 64);
#pragma unroll
    for (int c = 0; c < 7; c++) {
      acc4[c][0] += __shfl_xor(acc4[c][0], m, 64);
      acc4[c][1] += __shfl_xor(acc4[c][1], m, 64);
      acc4[c][2] += __shfl_xor(acc4[c][2], m, 64);
      acc4[c][3] += __shfl_xor(acc4[c][3], m, 64);
    }
  }
  if (esub == 0) {
    atomicAdd(&r_acc[q], rp);
#pragma unroll
    for (int c = 0; c < 7; c++)
#pragma unroll
      for (int r = 0; r < 4; r++)
        atomicAdd(&tT[(size_t)q * 32 + c * 4 + r], acc4[c][r]);
  }
}

// ---------------------------------------------------------------------------
// finalize: t = tT[q]/max(r,eps); echo = t @ class_reps; neg_dists (f32 out);
// BCE partial -> atomic.
// ---------------------------------------------------------------------------
__global__ void finalize(const float* __restrict__ tT, const float* __restrict__ r_acc,
                         const float* __restrict__ creps, const float* __restrict__ labels,
                         float* __restrict__ loss_acc, float* __restrict__ out) {
  __shared__ __align__(16) float cr[28 * 64];
  const int tid = threadIdx.x;  // 64
  for (int i = tid; i < 28 * 64; i += 64) cr[i] = creps[i];
  __syncthreads();

  const int q = blockIdx.x * 64 + tid;
  const float inv_r = 1.0f / fmaxf(r_acc[q], 1e-12f);
  float tv[28];
#pragma unroll
  for (int j = 0; j < 28; j++) tv[j] = tT[(size_t)q * 32 + j] * inv_r;

  f32x4 echo[16];
#pragma unroll
  for (int cg = 0; cg < 16; cg++) echo[cg] = f4zero();
#pragma unroll
  for (int j = 0; j < 28; j++) {
    float tj = tv[j];
#pragma unroll
    for (int cg = 0; cg < 16; cg++) echo[cg] += tj * *(f32x4*)(cr + j * 64 + cg * 4);
  }

  float lsum = 0.f;
#pragma unroll
  for (int j = 0; j < 28; j++) {
    f32x4 d2v = f4zero();
#pragma unroll
    for (int cg = 0; cg < 16; cg++) {
      f32x4 df = echo[cg] - *(f32x4*)(cr + j * 64 + cg * 4);
      d2v += df * df;
    }
    float d = sqrtf(d2v[0] + d2v[1] + d2v[2] + d2v[3]);
    out[1 + (size_t)q * 28 + j] = -d;
    float y = labels[(size_t)q * 28 + j];
    lsum += y * d + log1pf(expf(-d));  // BCEWithLogits(-d, y), d >= 0
  }
#pragma unroll
  for (int m = 1; m < 64; m <<= 1) lsum += __shfl_xor(lsum, m, 64);
  if (tid == 0) atomicAdd(loss_acc, lsum);
}

__global__ void write_loss(const float* __restrict__ loss_acc, float* __restrict__ out) {
  out[0] = loss_acc[0] * (1.0f / 114688.0f);
}

// ---------------------------------------------------------------------------
extern "C" void kernel_launch(void* const* d_in, const int* in_sizes, int n_in,
                              void* d_out, int out_size, void* d_ws, size_t ws_size,
                              hipStream_t stream) {
  // Resolve inputs BY ELEMENT COUNT (unique per input; permutation-proof).
  const float* features = nullptr;  // 4096*1024   = 4194304
  const float* labels   = nullptr;  // 4096*28     = 114688
  const float* ex_feat  = nullptr;  // 16384*1024  = 16777216
  const float* ex_cls   = nullptr;  // 16384*28    = 458752
  const float* g_w      = nullptr;  // 256*1024    = 262144
  const float* creps    = nullptr;  // 28*64       = 1792
  for (int i = 0; i < n_in; i++) {
    switch (in_sizes[i]) {
      case 4194304:  features = (const float*)d_in[i]; break;
      case 114688:   labels   = (const float*)d_in[i]; break;
      case 16777216: ex_feat  = (const float*)d_in[i]; break;
      case 458752:   ex_cls   = (const float*)d_in[i]; break;
      case 262144:   g_w      = (const float*)d_in[i]; break;
      case 1792:     creps    = (const float*)d_in[i]; break;
      default: break;
    }
  }
  float* out = (float*)d_out;  // f32: [loss(1)] ++ [neg_dists 4096*28]

  if (!features || !labels || !ex_feat || !ex_cls || !g_w || !creps ||
      ws_size < (141ull << 20)) {
    fill_sentinel<<<256, 256, 0, stream>>>(out, out_size);  // diagnostic
    return;
  }

  char* ws = (char*)d_ws;
  __bf16* f_n   = (__bf16*)(ws);                    // 2 MB   [4096][256]
  __bf16* ef_n  = (__bf16*)(ws + (2ull << 20));     // 8 MB   [16384][256]
  float*  vt    = (float*) (ws + (10ull << 20));    // 1.75MB [16384][28]
  __bf16* u     = (__bf16*)(ws + (12ull << 20));    // 128 MB [4096][16384]
  float*  tT    = (float*) (ws + (140ull << 20));   // 512 KB [4096][32]
  float*  r_acc = tT + 4096 * 32;                   // 16 KB
  float*  lossp = r_acc + 4096;                     // 4 B

  zero_f32<<<528, 256, 0, stream>>>(tT, 4096 * 32 + 4096 + 1);

  proj_l2norm<<<160, 256, 0, stream>>>(ex_feat, features, g_w, ef_n, f_n);
  build_vt_f32<<<64, 256, 0, stream>>>(ex_cls, vt);
  sim_s3<<<4096, 256, 0, stream>>>(f_n, ef_n, u);
  pv_accum<<<1024, 256, 0, stream>>>(u, vt, tT, r_acc);
  finalize<<<64, 64, 0, stream>>>(tT, r_acc, creps, labels, lossp, out);
  write_loss<<<1, 1, 0, stream>>>(lossp, out);
}

// Round 7
// 366.338 us; speedup vs baseline: 3.4361x; 3.4361x over previous
//
#include <hip/hip_runtime.h>

// ---------------------------------------------------------------------------
// minerva_35124242547419 — R7: re-fuse the S^3 + PV pipeline (R6 counters:
// pv_accum = 891 us @ 3% VALU, latency-bound; u round-trip = 256 MB HBM).
// I/O contract (established R4-R6): inputs f32 resolved BY SIZE, output f32.
//   f  = l2norm(features @ g_w.T)    [4096,256]  bf16
//   ef = l2norm(ex_features @ g_w.T) [16384,256] bf16
//   fused: S^T tile = ef_tile @ f^T (MFMA, Q in regs) -> u = S^3 (regs) ->
//          Us LDS -> PV MFMA: tT[c'][q] += vT[c'][e] u[q][e]; r[q] += |u|
//   t = tT/r ; echo = t @ class_reps ; neg_dists = -cdist ; BCE loss
// ---------------------------------------------------------------------------

typedef __bf16 bf16x8 __attribute__((ext_vector_type(8)));
typedef __bf16 bf16x4 __attribute__((ext_vector_type(4)));
typedef float  f32x4  __attribute__((ext_vector_type(4)));

__device__ __forceinline__ f32x4 f4zero() { f32x4 z = {0.f, 0.f, 0.f, 0.f}; return z; }

__device__ __forceinline__ f32x4 mfma16(bf16x8 a, bf16x8 b, f32x4 c) {
  return __builtin_amdgcn_mfma_f32_16x16x32_bf16(a, b, c, 0, 0, 0);
}

// 8 consecutive f32 -> bf16x8
__device__ __forceinline__ bf16x8 load8f(const float* p) {
  f32x4 a = *(const f32x4*)p;
  f32x4 b = *(const f32x4*)(p + 4);
  bf16x8 r;
  r[0] = (__bf16)a[0]; r[1] = (__bf16)a[1]; r[2] = (__bf16)a[2]; r[3] = (__bf16)a[3];
  r[4] = (__bf16)b[0]; r[5] = (__bf16)b[1]; r[6] = (__bf16)b[2]; r[7] = (__bf16)b[3];
  return r;
}

__global__ void zero_f32(float* __restrict__ p, int n) {
  for (int i = blockIdx.x * 256 + threadIdx.x; i < n; i += gridDim.x * 256) p[i] = 0.f;
}

__global__ void fill_sentinel(float* __restrict__ out, int n) {
  for (int i = blockIdx.x * 256 + threadIdx.x; i < n; i += gridDim.x * 256) out[i] = -1.0f;
}

// ---------------------------------------------------------------------------
// P = l2norm_rows(X @ W^T), X [M,1024] f32, W [256,1024] f32 -> P bf16.
// Block: 128 rows x 256 cols (full N). 4 waves 2x2.
// blocks 0..127 -> ex_features, 128..159 -> features.  (unchanged from R6)
// ---------------------------------------------------------------------------
__global__ __launch_bounds__(256, 1)
void proj_l2norm(const float* __restrict__ Xa, const float* __restrict__ Xb,
                 const float* __restrict__ W,
                 __bf16* __restrict__ Pa, __bf16* __restrict__ Pb) {
  __shared__ __align__(16) __bf16 Xs[128 * 40];
  __shared__ __align__(16) __bf16 Ws[256 * 40];
  __shared__ float nrm[256];
  __shared__ float invn[128];

  const int tid = threadIdx.x;
  const int w = tid >> 6, lane = tid & 63;
  const int quad = lane >> 4, l15 = lane & 15;
  const int wy = w >> 1, wx = w & 1;

  const float* X;
  __bf16* P;
  int row0;
  if (blockIdx.x < 128) { X = Xa; P = Pa; row0 = blockIdx.x * 128; }
  else                  { X = Xb; P = Pb; row0 = (blockIdx.x - 128) * 128; }

  f32x4 acc[4][8];
#pragma unroll
  for (int i = 0; i < 4; i++)
#pragma unroll
    for (int j = 0; j < 8; j++) acc[i][j] = f4zero();

  for (int ks = 0; ks < 32; ks++) {
    __syncthreads();
#pragma unroll
    for (int rep = 0; rep < 2; rep++) {
      int idx = rep * 256 + tid;
      int row = idx >> 2, c8 = idx & 3;
      *(bf16x8*)(Xs + row * 40 + c8 * 8) =
          load8f(X + (size_t)(row0 + row) * 1024 + ks * 32 + c8 * 8);
    }
#pragma unroll
    for (int rep = 0; rep < 4; rep++) {
      int idx = rep * 256 + tid;
      int row = idx >> 2, c8 = idx & 3;
      *(bf16x8*)(Ws + row * 40 + c8 * 8) =
          load8f(W + (size_t)row * 1024 + ks * 32 + c8 * 8);
    }
    __syncthreads();
    bf16x8 af[4], bfr[8];
#pragma unroll
    for (int mb = 0; mb < 4; mb++)
      af[mb] = *(bf16x8*)(Xs + (wy * 64 + mb * 16 + l15) * 40 + quad * 8);
#pragma unroll
    for (int nb = 0; nb < 8; nb++)
      bfr[nb] = *(bf16x8*)(Ws + (wx * 128 + nb * 16 + l15) * 40 + quad * 8);
#pragma unroll
    for (int mb = 0; mb < 4; mb++)
#pragma unroll
      for (int nb = 0; nb < 8; nb++)
        acc[mb][nb] = mfma16(af[mb], bfr[nb], acc[mb][nb]);
  }

  float part[4][4];
#pragma unroll
  for (int mb = 0; mb < 4; mb++)
#pragma unroll
    for (int r = 0; r < 4; r++) {
      float s = 0.f;
#pragma unroll
      for (int nb = 0; nb < 8; nb++) { float v = acc[mb][nb][r]; s += v * v; }
      part[mb][r] = s;
    }
#pragma unroll
  for (int m = 1; m < 16; m <<= 1)
#pragma unroll
    for (int mb = 0; mb < 4; mb++)
#pragma unroll
      for (int r = 0; r < 4; r++) part[mb][r] += __shfl_xor(part[mb][r], m, 64);

  if (l15 == 0) {
#pragma unroll
    for (int mb = 0; mb < 4; mb++)
#pragma unroll
      for (int r = 0; r < 4; r++)
        nrm[wx * 128 + wy * 64 + mb * 16 + quad * 4 + r] = part[mb][r];
  }
  __syncthreads();
  if (tid < 128) {
    float s = nrm[tid] + nrm[128 + tid];
    invn[tid] = 1.0f / fmaxf(sqrtf(s), 1e-12f);
  }
  __syncthreads();
#pragma unroll
  for (int mb = 0; mb < 4; mb++)
#pragma unroll
    for (int nb = 0; nb < 8; nb++)
#pragma unroll
      for (int r = 0; r < 4; r++) {
        int row = wy * 64 + mb * 16 + quad * 4 + r;
        int col = wx * 128 + nb * 16 + l15;
        P[(size_t)(row0 + row) * 256 + col] = (__bf16)(acc[mb][nb][r] * invn[row]);
      }
}

// ---------------------------------------------------------------------------
// vT[j][e] = l1norm_row(ex_classes)[e][j] bf16, rows 28..31 zero-padded.
// ---------------------------------------------------------------------------
__global__ void build_vt(const float* __restrict__ exc, __bf16* __restrict__ vT) {
  int e = blockIdx.x * 256 + threadIdx.x;
  float m[28];
  float s = 0.f;
#pragma unroll
  for (int j = 0; j < 28; j++) {
    m[j] = exc[(size_t)e * 28 + j];
    s += fabsf(m[j]);
  }
  float inv = 1.0f / fmaxf(s, 1e-12f);
#pragma unroll
  for (int j = 0; j < 28; j++) vT[(size_t)j * 16384 + e] = (__bf16)(m[j] * inv);
#pragma unroll
  for (int j = 28; j < 32; j++) vT[(size_t)j * 16384 + e] = (__bf16)0.0f;
}

// ---------------------------------------------------------------------------
// Fused flash-style pass (single-buffered).
//   grid 256 = 32 mtiles x 8 chunks (chunk = bid&7 -> XCD L2 locality).
//   Per block: 128 q x 2048 e (16 tiles of 128). Q frags in registers.
//   S^T tile [128e x 128q] MFMA -> cube (regs) -> Us [q][e] LDS ->
//   PV MFMA: accp[c'][q] += Vs x Us ; r from bf16 u (R6-consistent).
//   Outputs via atomics: tT [32][4096] (c'-major), r_acc [4096].
// ---------------------------------------------------------------------------
__global__ __launch_bounds__(256, 1)
void fused_sim(const __bf16* __restrict__ fn, const __bf16* __restrict__ efn,
               const __bf16* __restrict__ vTg,
               float* __restrict__ tT, float* __restrict__ r_acc) {
  __shared__ __align__(16) __bf16 Ks[128 * 264];  // ef tile [e][256]+8 pad, 66 KB
  __shared__ __align__(16) __bf16 Vs[32 * 136];   // vT tile [c'][128]+8 pad, 8.5 KB
  __shared__ __align__(16) __bf16 Us[128 * 136];  // u^T [q][128e]+8 pad, 34 KB

  const int tid = threadIdx.x, w = tid >> 6, lane = tid & 63;
  const int quad = lane >> 4, l15 = lane & 15;
  const int wy = w >> 1, wx = w & 1;
  const int chunk = blockIdx.x & 7, mtile = blockIdx.x >> 3;
  const int q0 = mtile * 128;
  const int e_base = chunk * 2048;

  // Q fragments in registers: wave's 64 q-rows x K=256 -> 32 frags (128 VGPR)
  bf16x8 qf[8][4];
#pragma unroll
  for (int ks = 0; ks < 8; ks++)
#pragma unroll
    for (int nb = 0; nb < 4; nb++)
      qf[ks][nb] = *(const bf16x8*)(fn + (size_t)(q0 + wx * 64 + nb * 16 + l15) * 256 +
                                    ks * 32 + quad * 8);

  float r_part[4] = {0.f, 0.f, 0.f, 0.f};
  f32x4 accp[2][2];
#pragma unroll
  for (int a = 0; a < 2; a++)
#pragma unroll
    for (int b = 0; b < 2; b++) accp[a][b] = f4zero();

  for (int t = 0; t < 16; t++) {
    const int e_t = e_base + t * 128;

    __syncthreads();  // prior PV reads of Us/Vs and S reads of Ks done
    // stage ef tile [128][256]: 4096 bf16x8, 16/thread
#pragma unroll
    for (int rep = 0; rep < 16; rep++) {
      int idx = rep * 256 + tid;
      int row = idx >> 5, c8 = idx & 31;
      *(bf16x8*)(Ks + row * 264 + c8 * 8) =
          *(const bf16x8*)(efn + (size_t)(e_t + row) * 256 + c8 * 8);
    }
    // stage vT tile [32][128]: 512 bf16x8, 2/thread
#pragma unroll
    for (int rep = 0; rep < 2; rep++) {
      int idx = rep * 256 + tid;
      int row = idx >> 4, c8 = idx & 15;
      *(bf16x8*)(Vs + row * 136 + c8 * 8) =
          *(const bf16x8*)(vTg + (size_t)row * 16384 + e_t + c8 * 8);
    }
    __syncthreads();  // staged data visible

    // S^T = K_tile . Q^T : rows = exemplars (m), cols = queries (n)
    f32x4 accs[4][4];
#pragma unroll
    for (int a = 0; a < 4; a++)
#pragma unroll
      for (int b = 0; b < 4; b++) accs[a][b] = f4zero();
#pragma unroll
    for (int ks = 0; ks < 8; ks++) {
      bf16x8 af[4];
#pragma unroll
      for (int mb = 0; mb < 4; mb++)
        af[mb] = *(bf16x8*)(Ks + (wy * 64 + mb * 16 + l15) * 264 + ks * 32 + quad * 8);
#pragma unroll
      for (int mb = 0; mb < 4; mb++)
#pragma unroll
        for (int nb = 0; nb < 4; nb++)
          accs[mb][nb] = mfma16(af[mb], qf[ks][nb], accs[mb][nb]);
    }

    // cube -> bf16 u; r from the SAME bf16 values (R6-consistent); pack to Us
#pragma unroll
    for (int mb = 0; mb < 4; mb++) {
      const int eo = wy * 64 + mb * 16 + quad * 4;
#pragma unroll
      for (int nb = 0; nb < 4; nb++) {
        const int q = wx * 64 + nb * 16 + l15;
        bf16x4 pk;
#pragma unroll
        for (int r = 0; r < 4; r++) {
          float s = accs[mb][nb][r];
          __bf16 ub = (__bf16)(s * s * s);
          pk[r] = ub;
          r_part[nb] += fabsf((float)ub);
        }
        *(bf16x4*)(Us + q * 136 + eo) = pk;
      }
    }
    __syncthreads();  // Us visible (and all Ks reads complete)

    // PV: accp[c'][q] += sum_e vT[c'][e] * u[q][e]   (k = e, 128 in 4 steps)
#pragma unroll
    for (int ks = 0; ks < 4; ks++) {
      bf16x8 vf[2], uf[2];
#pragma unroll
      for (int cb = 0; cb < 2; cb++)
        vf[cb] = *(bf16x8*)(Vs + (cb * 16 + l15) * 136 + ks * 32 + quad * 8);
#pragma unroll
      for (int qb = 0; qb < 2; qb++)
        uf[qb] = *(bf16x8*)(Us + (w * 32 + qb * 16 + l15) * 136 + ks * 32 + quad * 8);
#pragma unroll
      for (int cb = 0; cb < 2; cb++)
#pragma unroll
        for (int qb = 0; qb < 2; qb++)
          accp[cb][qb] = mfma16(vf[cb], uf[qb], accp[cb][qb]);
    }
  }

  // epilogue: |u| sums -> reduce across quads (same q col), atomics
#pragma unroll
  for (int nb = 0; nb < 4; nb++) {
    float v = r_part[nb];
    v += __shfl_xor(v, 16, 64);
    v += __shfl_xor(v, 32, 64);
    if (quad == 0) atomicAdd(&r_acc[q0 + wx * 64 + nb * 16 + l15], v);
  }
  // tT [c'][4096]: row = cb*16 + quad*4 + r, col = q0 + w*32 + qb*16 + l15
#pragma unroll
  for (int cb = 0; cb < 2; cb++)
#pragma unroll
    for (int qb = 0; qb < 2; qb++)
#pragma unroll
      for (int r = 0; r < 4; r++)
        atomicAdd(&tT[(size_t)(cb * 16 + quad * 4 + r) * 4096 + q0 + w * 32 + qb * 16 + l15],
                  accp[cb][qb][r]);
}

// ---------------------------------------------------------------------------
// finalize: t = tT[:,q]/max(r,eps); echo = t @ class_reps; neg_dists; BCE.
// tT layout: [32][4096] c'-major.
// ---------------------------------------------------------------------------
__global__ void finalize(const float* __restrict__ tT, const float* __restrict__ r_acc,
                         const float* __restrict__ creps, const float* __restrict__ labels,
                         float* __restrict__ loss_acc, float* __restrict__ out) {
  __shared__ __align__(16) float cr[28 * 64];
  const int tid = threadIdx.x;  // 64
  for (int i = tid; i < 28 * 64; i += 64) cr[i] = creps[i];
  __syncthreads();

  const int q = blockIdx.x * 64 + tid;
  const float inv_r = 1.0f / fmaxf(r_acc[q], 1e-12f);
  float tv[28];
#pragma unroll
  for (int j = 0; j < 28; j++) tv[j] = tT[(size_t)j * 4096 + q] * inv_r;

  f32x4 echo[16];
#pragma unroll
  for (int cg = 0; cg < 16; cg++) echo[cg] = f4zero();
#pragma unroll
  for (int j = 0; j < 28; j++) {
    float tj = tv[j];
#pragma unroll
    for (int cg = 0; cg < 16; cg++) echo[cg] += tj * *(f32x4*)(cr + j * 64 + cg * 4);
  }

  float lsum = 0.f;
#pragma unroll
  for (int j = 0; j < 28; j++) {
    f32x4 d2v = f4zero();
#pragma unroll
    for (int cg = 0; cg < 16; cg++) {
      f32x4 df = echo[cg] - *(f32x4*)(cr + j * 64 + cg * 4);
      d2v += df * df;
    }
    float d = sqrtf(d2v[0] + d2v[1] + d2v[2] + d2v[3]);
    out[1 + (size_t)q * 28 + j] = -d;
    float y = labels[(size_t)q * 28 + j];
    lsum += y * d + log1pf(expf(-d));  // BCEWithLogits(-d, y), d >= 0
  }
#pragma unroll
  for (int m = 1; m < 64; m <<= 1) lsum += __shfl_xor(lsum, m, 64);
  if (tid == 0) atomicAdd(loss_acc, lsum);
}

__global__ void write_loss(const float* __restrict__ loss_acc, float* __restrict__ out) {
  out[0] = loss_acc[0] * (1.0f / 114688.0f);
}

// ---------------------------------------------------------------------------
extern "C" void kernel_launch(void* const* d_in, const int* in_sizes, int n_in,
                              void* d_out, int out_size, void* d_ws, size_t ws_size,
                              hipStream_t stream) {
  // Resolve inputs BY ELEMENT COUNT (unique per input; permutation-proof).
  const float* features = nullptr;  // 4096*1024   = 4194304
  const float* labels   = nullptr;  // 4096*28     = 114688
  const float* ex_feat  = nullptr;  // 16384*1024  = 16777216
  const float* ex_cls   = nullptr;  // 16384*28    = 458752
  const float* g_w      = nullptr;  // 256*1024    = 262144
  const float* creps    = nullptr;  // 28*64       = 1792
  for (int i = 0; i < n_in; i++) {
    switch (in_sizes[i]) {
      case 4194304:  features = (const float*)d_in[i]; break;
      case 114688:   labels   = (const float*)d_in[i]; break;
      case 16777216: ex_feat  = (const float*)d_in[i]; break;
      case 458752:   ex_cls   = (const float*)d_in[i]; break;
      case 262144:   g_w      = (const float*)d_in[i]; break;
      case 1792:     creps    = (const float*)d_in[i]; break;
      default: break;
    }
  }
  float* out = (float*)d_out;  // f32: [loss(1)] ++ [neg_dists 4096*28]

  if (!features || !labels || !ex_feat || !ex_cls || !g_w || !creps ||
      ws_size < (16ull << 20)) {
    fill_sentinel<<<256, 256, 0, stream>>>(out, out_size);  // diagnostic
    return;
  }

  char* ws = (char*)d_ws;
  __bf16* f_n   = (__bf16*)(ws);                    // 2 MB   [4096][256]
  __bf16* ef_n  = (__bf16*)(ws + (2ull << 20));     // 8 MB   [16384][256]
  __bf16* vT    = (__bf16*)(ws + (10ull << 20));    // 1 MB   [32][16384]
  float*  tT    = (float*) (ws + (11ull << 20));    // 512 KB [32][4096]
  float*  r_acc = tT + 32 * 4096;                   // 16 KB
  float*  lossp = r_acc + 4096;                     // 4 B

  zero_f32<<<528, 256, 0, stream>>>(tT, 32 * 4096 + 4096 + 1);

  proj_l2norm<<<160, 256, 0, stream>>>(ex_feat, features, g_w, ef_n, f_n);
  build_vt<<<64, 256, 0, stream>>>(ex_cls, vT);
  fused_sim<<<256, 256, 0, stream>>>(f_n, ef_n, vT, tT, r_acc);
  finalize<<<64, 64, 0, stream>>>(tT, r_acc, creps, labels, lossp, out);
  write_loss<<<1, 1, 0, stream>>>(lossp, out);
}

// Round 8
// 344.081 us; speedup vs baseline: 3.6583x; 1.0647x over previous
//
#include <hip/hip_runtime.h>

// ---------------------------------------------------------------------------
// minerva_35124242547419 — R8: occupancy round.
// R7 counters: fused_sim 120us @ Occupancy 11% (1 block/CU, 111KB LDS);
// proj grid=160 < 256 CUs. Fix: 64e-tiles -> 55.5KB LDS, 512 blocks (2/CU);
// proj 64-row blocks -> 320 blocks, BK=64.
// I/O contract (R4-R6): f32 inputs resolved BY SIZE, f32 output.
// ---------------------------------------------------------------------------

typedef __bf16 bf16x8 __attribute__((ext_vector_type(8)));
typedef __bf16 bf16x4 __attribute__((ext_vector_type(4)));
typedef float  f32x4  __attribute__((ext_vector_type(4)));

__device__ __forceinline__ f32x4 f4zero() { f32x4 z = {0.f, 0.f, 0.f, 0.f}; return z; }

__device__ __forceinline__ f32x4 mfma16(bf16x8 a, bf16x8 b, f32x4 c) {
  return __builtin_amdgcn_mfma_f32_16x16x32_bf16(a, b, c, 0, 0, 0);
}

// 8 consecutive f32 -> bf16x8
__device__ __forceinline__ bf16x8 load8f(const float* p) {
  f32x4 a = *(const f32x4*)p;
  f32x4 b = *(const f32x4*)(p + 4);
  bf16x8 r;
  r[0] = (__bf16)a[0]; r[1] = (__bf16)a[1]; r[2] = (__bf16)a[2]; r[3] = (__bf16)a[3];
  r[4] = (__bf16)b[0]; r[5] = (__bf16)b[1]; r[6] = (__bf16)b[2]; r[7] = (__bf16)b[3];
  return r;
}

__global__ void zero_f32(float* __restrict__ p, int n) {
  for (int i = blockIdx.x * 256 + threadIdx.x; i < n; i += gridDim.x * 256) p[i] = 0.f;
}

__global__ void fill_sentinel(float* __restrict__ out, int n) {
  for (int i = blockIdx.x * 256 + threadIdx.x; i < n; i += gridDim.x * 256) out[i] = -1.0f;
}

// ---------------------------------------------------------------------------
// P = l2norm_rows(X @ W^T). Block: 64 rows x 256 cols, BK=64, 16 k-iters.
// 4 waves side-by-side in N (wave w: cols w*64..w*64+63, rows 0..63).
// blocks 0..255 -> ex_features, 256..319 -> features. LDS 46 KB.
// ---------------------------------------------------------------------------
__global__ __launch_bounds__(256, 2)
void proj_l2norm(const float* __restrict__ Xa, const float* __restrict__ Xb,
                 const float* __restrict__ W,
                 __bf16* __restrict__ Pa, __bf16* __restrict__ Pb) {
  __shared__ __align__(16) __bf16 Xs[64 * 72];    // 9 KB
  __shared__ __align__(16) __bf16 Ws[256 * 72];   // 36 KB
  __shared__ float nrmW[4 * 64];
  __shared__ float invn[64];

  const int tid = threadIdx.x;
  const int w = tid >> 6, lane = tid & 63;
  const int quad = lane >> 4, l15 = lane & 15;

  const float* X;
  __bf16* P;
  int row0;
  if (blockIdx.x < 256) { X = Xa; P = Pa; row0 = blockIdx.x * 64; }
  else                  { X = Xb; P = Pb; row0 = (blockIdx.x - 256) * 64; }

  f32x4 acc[4][4];
#pragma unroll
  for (int i = 0; i < 4; i++)
#pragma unroll
    for (int j = 0; j < 4; j++) acc[i][j] = f4zero();

  for (int ks = 0; ks < 16; ks++) {
    __syncthreads();
    // Xs [64][64]: 512 bf16x8, 2/thread
#pragma unroll
    for (int rep = 0; rep < 2; rep++) {
      int idx = rep * 256 + tid;
      int row = idx >> 3, c8 = idx & 7;
      *(bf16x8*)(Xs + row * 72 + c8 * 8) =
          load8f(X + (size_t)(row0 + row) * 1024 + ks * 64 + c8 * 8);
    }
    // Ws [256][64]: 2048 bf16x8, 8/thread
#pragma unroll
    for (int rep = 0; rep < 8; rep++) {
      int idx = rep * 256 + tid;
      int row = idx >> 3, c8 = idx & 7;
      *(bf16x8*)(Ws + row * 72 + c8 * 8) =
          load8f(W + (size_t)row * 1024 + ks * 64 + c8 * 8);
    }
    __syncthreads();
#pragma unroll
    for (int ksub = 0; ksub < 2; ksub++) {
      bf16x8 af[4], bfr[4];
#pragma unroll
      for (int mb = 0; mb < 4; mb++)
        af[mb] = *(bf16x8*)(Xs + (mb * 16 + l15) * 72 + ksub * 32 + quad * 8);
#pragma unroll
      for (int nb = 0; nb < 4; nb++)
        bfr[nb] = *(bf16x8*)(Ws + (w * 64 + nb * 16 + l15) * 72 + ksub * 32 + quad * 8);
#pragma unroll
      for (int mb = 0; mb < 4; mb++)
#pragma unroll
        for (int nb = 0; nb < 4; nb++)
          acc[mb][nb] = mfma16(af[mb], bfr[nb], acc[mb][nb]);
    }
  }

  // row sum-of-squares: in-lane over nb, shfl over l15 (cols), cross-wave via LDS
  float part[4][4];
#pragma unroll
  for (int mb = 0; mb < 4; mb++)
#pragma unroll
    for (int r = 0; r < 4; r++) {
      float s = 0.f;
#pragma unroll
      for (int nb = 0; nb < 4; nb++) { float v = acc[mb][nb][r]; s += v * v; }
      part[mb][r] = s;
    }
#pragma unroll
  for (int m = 1; m < 16; m <<= 1)
#pragma unroll
    for (int mb = 0; mb < 4; mb++)
#pragma unroll
      for (int r = 0; r < 4; r++) part[mb][r] += __shfl_xor(part[mb][r], m, 64);

  if (l15 == 0) {
#pragma unroll
    for (int mb = 0; mb < 4; mb++)
#pragma unroll
      for (int r = 0; r < 4; r++)
        nrmW[w * 64 + mb * 16 + quad * 4 + r] = part[mb][r];
  }
  __syncthreads();
  if (tid < 64) {
    float s = nrmW[tid] + nrmW[64 + tid] + nrmW[128 + tid] + nrmW[192 + tid];
    invn[tid] = 1.0f / fmaxf(sqrtf(s), 1e-12f);
  }
  __syncthreads();
#pragma unroll
  for (int mb = 0; mb < 4; mb++)
#pragma unroll
    for (int nb = 0; nb < 4; nb++)
#pragma unroll
      for (int r = 0; r < 4; r++) {
        int row = mb * 16 + quad * 4 + r;
        int col = w * 64 + nb * 16 + l15;
        P[(size_t)(row0 + row) * 256 + col] = (__bf16)(acc[mb][nb][r] * invn[row]);
      }
}

// ---------------------------------------------------------------------------
// vT[j][e] = l1norm_row(ex_classes)[e][j] bf16, rows 28..31 zero-padded.
// ---------------------------------------------------------------------------
__global__ void build_vt(const float* __restrict__ exc, __bf16* __restrict__ vT) {
  int e = blockIdx.x * 256 + threadIdx.x;
  float m[28];
  float s = 0.f;
#pragma unroll
  for (int j = 0; j < 28; j++) {
    m[j] = exc[(size_t)e * 28 + j];
    s += fabsf(m[j]);
  }
  float inv = 1.0f / fmaxf(s, 1e-12f);
#pragma unroll
  for (int j = 0; j < 28; j++) vT[(size_t)j * 16384 + e] = (__bf16)(m[j] * inv);
#pragma unroll
  for (int j = 28; j < 32; j++) vT[(size_t)j * 16384 + e] = (__bf16)0.0f;
}

// ---------------------------------------------------------------------------
// Fused flash-style pass, 64e-tile / 55.5 KB LDS / 2 blocks per CU.
//   grid 512 = 32 mtiles x 16 chunks (chunk = bid&15; bid&7 -> XCD).
//   Per block: 128 q x 1024 e (16 tiles of 64e). Q frags in registers.
//   S^T tile [64e x 128q] MFMA -> u = S^3 -> Us LDS -> PV MFMA ->
//   atomics: tT [32][4096] (c'-major), r_acc [4096] (r from bf16 u).
// ---------------------------------------------------------------------------
__global__ __launch_bounds__(256, 2)
void fused_sim(const __bf16* __restrict__ fn, const __bf16* __restrict__ efn,
               const __bf16* __restrict__ vTg,
               float* __restrict__ tT, float* __restrict__ r_acc) {
  __shared__ __align__(16) __bf16 Ks[64 * 264];  // ef tile [e][256]+8 pad, 33 KB
  __shared__ __align__(16) __bf16 Vs[32 * 72];   // vT tile [c'][64]+8 pad, 4.5 KB
  __shared__ __align__(16) __bf16 Us[128 * 72];  // u^T [q][64e]+8 pad, 18 KB

  const int tid = threadIdx.x, w = tid >> 6, lane = tid & 63;
  const int quad = lane >> 4, l15 = lane & 15;
  const int wy = w >> 1, wx = w & 1;
  const int chunk = blockIdx.x & 15, mtile = blockIdx.x >> 4;
  const int q0 = mtile * 128;
  const int e_base = chunk * 1024;

  // Q fragments in registers: wave's 64 q-rows x K=256 -> 32 frags (128 VGPR)
  bf16x8 qf[8][4];
#pragma unroll
  for (int ks = 0; ks < 8; ks++)
#pragma unroll
    for (int nb = 0; nb < 4; nb++)
      qf[ks][nb] = *(const bf16x8*)(fn + (size_t)(q0 + wx * 64 + nb * 16 + l15) * 256 +
                                    ks * 32 + quad * 8);

  float r_part[4] = {0.f, 0.f, 0.f, 0.f};
  f32x4 accp[2][2];
#pragma unroll
  for (int a = 0; a < 2; a++)
#pragma unroll
    for (int b = 0; b < 2; b++) accp[a][b] = f4zero();

  for (int t = 0; t < 16; t++) {
    const int e_t = e_base + t * 64;

    __syncthreads();  // prior S reads of Ks + PV reads of Us/Vs done
    // stage ef tile [64][256]: 2048 bf16x8, 8/thread
#pragma unroll
    for (int rep = 0; rep < 8; rep++) {
      int idx = rep * 256 + tid;
      int row = idx >> 5, c8 = idx & 31;
      *(bf16x8*)(Ks + row * 264 + c8 * 8) =
          *(const bf16x8*)(efn + (size_t)(e_t + row) * 256 + c8 * 8);
    }
    // stage vT tile [32][64]: 256 bf16x8, 1/thread
    {
      int row = tid >> 3, c8 = tid & 7;
      *(bf16x8*)(Vs + row * 72 + c8 * 8) =
          *(const bf16x8*)(vTg + (size_t)row * 16384 + e_t + c8 * 8);
    }
    __syncthreads();  // staged data visible

    // S^T = K_tile . Q^T : rows = exemplars (m, 64), cols = queries (n, 128)
    f32x4 accs[2][4];
#pragma unroll
    for (int a = 0; a < 2; a++)
#pragma unroll
      for (int b = 0; b < 4; b++) accs[a][b] = f4zero();
#pragma unroll
    for (int ks = 0; ks < 8; ks++) {
      bf16x8 af[2];
#pragma unroll
      for (int mb = 0; mb < 2; mb++)
        af[mb] = *(bf16x8*)(Ks + (wy * 32 + mb * 16 + l15) * 264 + ks * 32 + quad * 8);
#pragma unroll
      for (int mb = 0; mb < 2; mb++)
#pragma unroll
        for (int nb = 0; nb < 4; nb++)
          accs[mb][nb] = mfma16(af[mb], qf[ks][nb], accs[mb][nb]);
    }

    // cube -> bf16 u; r from the SAME bf16 values; pack to Us[q][e_local]
#pragma unroll
    for (int mb = 0; mb < 2; mb++) {
      const int eo = wy * 32 + mb * 16 + quad * 4;
#pragma unroll
      for (int nb = 0; nb < 4; nb++) {
        const int q = wx * 64 + nb * 16 + l15;
        bf16x4 pk;
#pragma unroll
        for (int r = 0; r < 4; r++) {
          float s = accs[mb][nb][r];
          __bf16 ub = (__bf16)(s * s * s);
          pk[r] = ub;
          r_part[nb] += fabsf((float)ub);
        }
        *(bf16x4*)(Us + q * 72 + eo) = pk;
      }
    }
    __syncthreads();  // Us visible

    // PV: accp[c'][q] += sum_e vT[c'][e] * u[q][e]  (k = 64 in 2 steps)
#pragma unroll
    for (int ks = 0; ks < 2; ks++) {
      bf16x8 vf[2], uf[2];
#pragma unroll
      for (int cb = 0; cb < 2; cb++)
        vf[cb] = *(bf16x8*)(Vs + (cb * 16 + l15) * 72 + ks * 32 + quad * 8);
#pragma unroll
      for (int qb = 0; qb < 2; qb++)
        uf[qb] = *(bf16x8*)(Us + (w * 32 + qb * 16 + l15) * 72 + ks * 32 + quad * 8);
#pragma unroll
      for (int cb = 0; cb < 2; cb++)
#pragma unroll
        for (int qb = 0; qb < 2; qb++)
          accp[cb][qb] = mfma16(vf[cb], uf[qb], accp[cb][qb]);
    }
  }

  // epilogue: |u| sums -> reduce across quads (same q col), atomics
#pragma unroll
  for (int nb = 0; nb < 4; nb++) {
    float v = r_part[nb];
    v += __shfl_xor(v, 16, 64);
    v += __shfl_xor(v, 32, 64);
    if (quad == 0) atomicAdd(&r_acc[q0 + wx * 64 + nb * 16 + l15], v);
  }
  // tT [c'][4096]: row = cb*16 + quad*4 + r, col = q0 + w*32 + qb*16 + l15
#pragma unroll
  for (int cb = 0; cb < 2; cb++)
#pragma unroll
    for (int qb = 0; qb < 2; qb++)
#pragma unroll
      for (int r = 0; r < 4; r++)
        atomicAdd(&tT[(size_t)(cb * 16 + quad * 4 + r) * 4096 + q0 + w * 32 + qb * 16 + l15],
                  accp[cb][qb][r]);
}

// ---------------------------------------------------------------------------
// finalize: t = tT[:,q]/max(r,eps); echo = t @ class_reps; neg_dists; BCE.
// tT layout: [32][4096] c'-major.
// ---------------------------------------------------------------------------
__global__ void finalize(const float* __restrict__ tT, const float* __restrict__ r_acc,
                         const float* __restrict__ creps, const float* __restrict__ labels,
                         float* __restrict__ loss_acc, float* __restrict__ out) {
  __shared__ __align__(16) float cr[28 * 64];
  const int tid = threadIdx.x;  // 64
  for (int i = tid; i < 28 * 64; i += 64) cr[i] = creps[i];
  __syncthreads();

  const int q = blockIdx.x * 64 + tid;
  const float inv_r = 1.0f / fmaxf(r_acc[q], 1e-12f);
  float tv[28];
#pragma unroll
  for (int j = 0; j < 28; j++) tv[j] = tT[(size_t)j * 4096 + q] * inv_r;

  f32x4 echo[16];
#pragma unroll
  for (int cg = 0; cg < 16; cg++) echo[cg] = f4zero();
#pragma unroll
  for (int j = 0; j < 28; j++) {
    float tj = tv[j];
#pragma unroll
    for (int cg = 0; cg < 16; cg++) echo[cg] += tj * *(f32x4*)(cr + j * 64 + cg * 4);
  }

  float lsum = 0.f;
#pragma unroll
  for (int j = 0; j < 28; j++) {
    f32x4 d2v = f4zero();
#pragma unroll
    for (int cg = 0; cg < 16; cg++) {
      f32x4 df = echo[cg] - *(f32x4*)(cr + j * 64 + cg * 4);
      d2v += df * df;
    }
    float d = sqrtf(d2v[0] + d2v[1] + d2v[2] + d2v[3]);
    out[1 + (size_t)q * 28 + j] = -d;
    float y = labels[(size_t)q * 28 + j];
    lsum += y * d + log1pf(expf(-d));  // BCEWithLogits(-d, y), d >= 0
  }
#pragma unroll
  for (int m = 1; m < 64; m <<= 1) lsum += __shfl_xor(lsum, m, 64);
  if (tid == 0) atomicAdd(loss_acc, lsum);
}

__global__ void write_loss(const float* __restrict__ loss_acc, float* __restrict__ out) {
  out[0] = loss_acc[0] * (1.0f / 114688.0f);
}

// ---------------------------------------------------------------------------
extern "C" void kernel_launch(void* const* d_in, const int* in_sizes, int n_in,
                              void* d_out, int out_size, void* d_ws, size_t ws_size,
                              hipStream_t stream) {
  // Resolve inputs BY ELEMENT COUNT (unique per input; permutation-proof).
  const float* features = nullptr;  // 4096*1024   = 4194304
  const float* labels   = nullptr;  // 4096*28     = 114688
  const float* ex_feat  = nullptr;  // 16384*1024  = 16777216
  const float* ex_cls   = nullptr;  // 16384*28    = 458752
  const float* g_w      = nullptr;  // 256*1024    = 262144
  const float* creps    = nullptr;  // 28*64       = 1792
  for (int i = 0; i < n_in; i++) {
    switch (in_sizes[i]) {
      case 4194304:  features = (const float*)d_in[i]; break;
      case 114688:   labels   = (const float*)d_in[i]; break;
      case 16777216: ex_feat  = (const float*)d_in[i]; break;
      case 458752:   ex_cls   = (const float*)d_in[i]; break;
      case 262144:   g_w      = (const float*)d_in[i]; break;
      case 1792:     creps    = (const float*)d_in[i]; break;
      default: break;
    }
  }
  float* out = (float*)d_out;  // f32: [loss(1)] ++ [neg_dists 4096*28]

  if (!features || !labels || !ex_feat || !ex_cls || !g_w || !creps ||
      ws_size < (16ull << 20)) {
    fill_sentinel<<<256, 256, 0, stream>>>(out, out_size);  // diagnostic
    return;
  }

  char* ws = (char*)d_ws;
  __bf16* f_n   = (__bf16*)(ws);                    // 2 MB   [4096][256]
  __bf16* ef_n  = (__bf16*)(ws + (2ull << 20));     // 8 MB   [16384][256]
  __bf16* vT    = (__bf16*)(ws + (10ull << 20));    // 1 MB   [32][16384]
  float*  tT    = (float*) (ws + (11ull << 20));    // 512 KB [32][4096]
  float*  r_acc = tT + 32 * 4096;                   // 16 KB
  float*  lossp = r_acc + 4096;                     // 4 B

  zero_f32<<<528, 256, 0, stream>>>(tT, 32 * 4096 + 4096 + 1);

  proj_l2norm<<<320, 256, 0, stream>>>(ex_feat, features, g_w, ef_n, f_n);
  build_vt<<<64, 256, 0, stream>>>(ex_cls, vT);
  fused_sim<<<512, 256, 0, stream>>>(f_n, ef_n, vT, tT, r_acc);
  finalize<<<64, 64, 0, stream>>>(tT, r_acc, creps, labels, lossp, out);
  write_loss<<<1, 1, 0, stream>>>(lossp, out);
}

// Round 9
// 257.078 us; speedup vs baseline: 4.8964x; 1.3384x over previous
//
#include <hip/hip_runtime.h>

// ---------------------------------------------------------------------------
// minerva_35124242547419 — R9: parallelism round.
// R8 counters: finalize 86-145us @ 0.003% occupancy (4096 threads total!);
// proj 104us @ 13.8% occ (grid 320, 1 block/CU most CUs, barrier-naked).
// Fix: finalize -> wave-per-query (1024x256); proj -> 32-row blocks, grid 640,
// 3 blocks/CU. fused_sim (<=80us, 2 blocks/CU) untouched.
// I/O contract (R4-R6): f32 inputs resolved BY SIZE, f32 output.
// ---------------------------------------------------------------------------

typedef __bf16 bf16x8 __attribute__((ext_vector_type(8)));
typedef __bf16 bf16x4 __attribute__((ext_vector_type(4)));
typedef float  f32x4  __attribute__((ext_vector_type(4)));

__device__ __forceinline__ f32x4 f4zero() { f32x4 z = {0.f, 0.f, 0.f, 0.f}; return z; }

__device__ __forceinline__ f32x4 mfma16(bf16x8 a, bf16x8 b, f32x4 c) {
  return __builtin_amdgcn_mfma_f32_16x16x32_bf16(a, b, c, 0, 0, 0);
}

// 8 consecutive f32 -> bf16x8
__device__ __forceinline__ bf16x8 load8f(const float* p) {
  f32x4 a = *(const f32x4*)p;
  f32x4 b = *(const f32x4*)(p + 4);
  bf16x8 r;
  r[0] = (__bf16)a[0]; r[1] = (__bf16)a[1]; r[2] = (__bf16)a[2]; r[3] = (__bf16)a[3];
  r[4] = (__bf16)b[0]; r[5] = (__bf16)b[1]; r[6] = (__bf16)b[2]; r[7] = (__bf16)b[3];
  return r;
}

__global__ void zero_f32(float* __restrict__ p, int n) {
  for (int i = blockIdx.x * 256 + threadIdx.x; i < n; i += gridDim.x * 256) p[i] = 0.f;
}

__global__ void fill_sentinel(float* __restrict__ out, int n) {
  for (int i = blockIdx.x * 256 + threadIdx.x; i < n; i += gridDim.x * 256) out[i] = -1.0f;
}

// ---------------------------------------------------------------------------
// P = l2norm_rows(X @ W^T). Block: 32 rows x 256 cols, BK=64, 16 k-iters.
// 4 waves side-by-side in N (wave w: cols w*64..+63, rows 0..31).
// blocks 0..511 -> ex_features, 512..639 -> features. LDS ~42 KB, 3 blk/CU.
// ---------------------------------------------------------------------------
__global__ __launch_bounds__(256, 3)
void proj_l2norm(const float* __restrict__ Xa, const float* __restrict__ Xb,
                 const float* __restrict__ W,
                 __bf16* __restrict__ Pa, __bf16* __restrict__ Pb) {
  __shared__ __align__(16) __bf16 Xs[32 * 72];    // 4.5 KB
  __shared__ __align__(16) __bf16 Ws[256 * 72];   // 36 KB
  __shared__ float nrmW[4 * 32];
  __shared__ float invn[32];

  const int tid = threadIdx.x;
  const int w = tid >> 6, lane = tid & 63;
  const int quad = lane >> 4, l15 = lane & 15;

  const float* X;
  __bf16* P;
  int row0;
  if (blockIdx.x < 512) { X = Xa; P = Pa; row0 = blockIdx.x * 32; }
  else                  { X = Xb; P = Pb; row0 = (blockIdx.x - 512) * 32; }

  f32x4 acc[2][4];
#pragma unroll
  for (int i = 0; i < 2; i++)
#pragma unroll
    for (int j = 0; j < 4; j++) acc[i][j] = f4zero();

  for (int ks = 0; ks < 16; ks++) {
    __syncthreads();
    // Xs [32][64]: 256 bf16x8, 1/thread
    {
      int row = tid >> 3, c8 = tid & 7;
      *(bf16x8*)(Xs + row * 72 + c8 * 8) =
          load8f(X + (size_t)(row0 + row) * 1024 + ks * 64 + c8 * 8);
    }
    // Ws [256][64]: 2048 bf16x8, 8/thread
#pragma unroll
    for (int rep = 0; rep < 8; rep++) {
      int idx = rep * 256 + tid;
      int row = idx >> 3, c8 = idx & 7;
      *(bf16x8*)(Ws + row * 72 + c8 * 8) =
          load8f(W + (size_t)row * 1024 + ks * 64 + c8 * 8);
    }
    __syncthreads();
#pragma unroll
    for (int ksub = 0; ksub < 2; ksub++) {
      bf16x8 af[2], bfr[4];
#pragma unroll
      for (int mb = 0; mb < 2; mb++)
        af[mb] = *(bf16x8*)(Xs + (mb * 16 + l15) * 72 + ksub * 32 + quad * 8);
#pragma unroll
      for (int nb = 0; nb < 4; nb++)
        bfr[nb] = *(bf16x8*)(Ws + (w * 64 + nb * 16 + l15) * 72 + ksub * 32 + quad * 8);
#pragma unroll
      for (int mb = 0; mb < 2; mb++)
#pragma unroll
        for (int nb = 0; nb < 4; nb++)
          acc[mb][nb] = mfma16(af[mb], bfr[nb], acc[mb][nb]);
    }
  }

  // row sum-of-squares: in-lane over nb, shfl over l15, cross-wave via LDS
  float part[2][4];
#pragma unroll
  for (int mb = 0; mb < 2; mb++)
#pragma unroll
    for (int r = 0; r < 4; r++) {
      float s = 0.f;
#pragma unroll
      for (int nb = 0; nb < 4; nb++) { float v = acc[mb][nb][r]; s += v * v; }
      part[mb][r] = s;
    }
#pragma unroll
  for (int m = 1; m < 16; m <<= 1)
#pragma unroll
    for (int mb = 0; mb < 2; mb++)
#pragma unroll
      for (int r = 0; r < 4; r++) part[mb][r] += __shfl_xor(part[mb][r], m, 64);

  if (l15 == 0) {
#pragma unroll
    for (int mb = 0; mb < 2; mb++)
#pragma unroll
      for (int r = 0; r < 4; r++)
        nrmW[w * 32 + mb * 16 + quad * 4 + r] = part[mb][r];
  }
  __syncthreads();
  if (tid < 32) {
    float s = nrmW[tid] + nrmW[32 + tid] + nrmW[64 + tid] + nrmW[96 + tid];
    invn[tid] = 1.0f / fmaxf(sqrtf(s), 1e-12f);
  }
  __syncthreads();
#pragma unroll
  for (int mb = 0; mb < 2; mb++)
#pragma unroll
    for (int nb = 0; nb < 4; nb++)
#pragma unroll
      for (int r = 0; r < 4; r++) {
        int row = mb * 16 + quad * 4 + r;
        int col = w * 64 + nb * 16 + l15;
        P[(size_t)(row0 + row) * 256 + col] = (__bf16)(acc[mb][nb][r] * invn[row]);
      }
}

// ---------------------------------------------------------------------------
// vT[j][e] = l1norm_row(ex_classes)[e][j] bf16, rows 28..31 zero-padded.
// ---------------------------------------------------------------------------
__global__ void build_vt(const float* __restrict__ exc, __bf16* __restrict__ vT) {
  int e = blockIdx.x * 256 + threadIdx.x;
  float m[28];
  float s = 0.f;
#pragma unroll
  for (int j = 0; j < 28; j++) {
    m[j] = exc[(size_t)e * 28 + j];
    s += fabsf(m[j]);
  }
  float inv = 1.0f / fmaxf(s, 1e-12f);
#pragma unroll
  for (int j = 0; j < 28; j++) vT[(size_t)j * 16384 + e] = (__bf16)(m[j] * inv);
#pragma unroll
  for (int j = 28; j < 32; j++) vT[(size_t)j * 16384 + e] = (__bf16)0.0f;
}

// ---------------------------------------------------------------------------
// Fused flash-style pass (unchanged from R8: 64e-tile, 55.5 KB, 2 blk/CU).
// ---------------------------------------------------------------------------
__global__ __launch_bounds__(256, 2)
void fused_sim(const __bf16* __restrict__ fn, const __bf16* __restrict__ efn,
               const __bf16* __restrict__ vTg,
               float* __restrict__ tT, float* __restrict__ r_acc) {
  __shared__ __align__(16) __bf16 Ks[64 * 264];
  __shared__ __align__(16) __bf16 Vs[32 * 72];
  __shared__ __align__(16) __bf16 Us[128 * 72];

  const int tid = threadIdx.x, w = tid >> 6, lane = tid & 63;
  const int quad = lane >> 4, l15 = lane & 15;
  const int wy = w >> 1, wx = w & 1;
  const int chunk = blockIdx.x & 15, mtile = blockIdx.x >> 4;
  const int q0 = mtile * 128;
  const int e_base = chunk * 1024;

  bf16x8 qf[8][4];
#pragma unroll
  for (int ks = 0; ks < 8; ks++)
#pragma unroll
    for (int nb = 0; nb < 4; nb++)
      qf[ks][nb] = *(const bf16x8*)(fn + (size_t)(q0 + wx * 64 + nb * 16 + l15) * 256 +
                                    ks * 32 + quad * 8);

  float r_part[4] = {0.f, 0.f, 0.f, 0.f};
  f32x4 accp[2][2];
#pragma unroll
  for (int a = 0; a < 2; a++)
#pragma unroll
    for (int b = 0; b < 2; b++) accp[a][b] = f4zero();

  for (int t = 0; t < 16; t++) {
    const int e_t = e_base + t * 64;

    __syncthreads();
#pragma unroll
    for (int rep = 0; rep < 8; rep++) {
      int idx = rep * 256 + tid;
      int row = idx >> 5, c8 = idx & 31;
      *(bf16x8*)(Ks + row * 264 + c8 * 8) =
          *(const bf16x8*)(efn + (size_t)(e_t + row) * 256 + c8 * 8);
    }
    {
      int row = tid >> 3, c8 = tid & 7;
      *(bf16x8*)(Vs + row * 72 + c8 * 8) =
          *(const bf16x8*)(vTg + (size_t)row * 16384 + e_t + c8 * 8);
    }
    __syncthreads();

    f32x4 accs[2][4];
#pragma unroll
    for (int a = 0; a < 2; a++)
#pragma unroll
      for (int b = 0; b < 4; b++) accs[a][b] = f4zero();
#pragma unroll
    for (int ks = 0; ks < 8; ks++) {
      bf16x8 af[2];
#pragma unroll
      for (int mb = 0; mb < 2; mb++)
        af[mb] = *(bf16x8*)(Ks + (wy * 32 + mb * 16 + l15) * 264 + ks * 32 + quad * 8);
#pragma unroll
      for (int mb = 0; mb < 2; mb++)
#pragma unroll
        for (int nb = 0; nb < 4; nb++)
          accs[mb][nb] = mfma16(af[mb], qf[ks][nb], accs[mb][nb]);
    }

#pragma unroll
    for (int mb = 0; mb < 2; mb++) {
      const int eo = wy * 32 + mb * 16 + quad * 4;
#pragma unroll
      for (int nb = 0; nb < 4; nb++) {
        const int q = wx * 64 + nb * 16 + l15;
        bf16x4 pk;
#pragma unroll
        for (int r = 0; r < 4; r++) {
          float s = accs[mb][nb][r];
          __bf16 ub = (__bf16)(s * s * s);
          pk[r] = ub;
          r_part[nb] += fabsf((float)ub);
        }
        *(bf16x4*)(Us + q * 72 + eo) = pk;
      }
    }
    __syncthreads();

#pragma unroll
    for (int ks = 0; ks < 2; ks++) {
      bf16x8 vf[2], uf[2];
#pragma unroll
      for (int cb = 0; cb < 2; cb++)
        vf[cb] = *(bf16x8*)(Vs + (cb * 16 + l15) * 72 + ks * 32 + quad * 8);
#pragma unroll
      for (int qb = 0; qb < 2; qb++)
        uf[qb] = *(bf16x8*)(Us + (w * 32 + qb * 16 + l15) * 72 + ks * 32 + quad * 8);
#pragma unroll
      for (int cb = 0; cb < 2; cb++)
#pragma unroll
        for (int qb = 0; qb < 2; qb++)
          accp[cb][qb] = mfma16(vf[cb], uf[qb], accp[cb][qb]);
    }
  }

#pragma unroll
  for (int nb = 0; nb < 4; nb++) {
    float v = r_part[nb];
    v += __shfl_xor(v, 16, 64);
    v += __shfl_xor(v, 32, 64);
    if (quad == 0) atomicAdd(&r_acc[q0 + wx * 64 + nb * 16 + l15], v);
  }
#pragma unroll
  for (int cb = 0; cb < 2; cb++)
#pragma unroll
    for (int qb = 0; qb < 2; qb++)
#pragma unroll
      for (int r = 0; r < 4; r++)
        atomicAdd(&tT[(size_t)(cb * 16 + quad * 4 + r) * 4096 + q0 + w * 32 + qb * 16 + l15],
                  accp[cb][qb][r]);
}

// ---------------------------------------------------------------------------
// finalize: WAVE-PER-QUERY. Block = 256 (4 waves = 4 queries), grid 1024.
// lane = class-rep dim c (64). tv_j broadcast by shfl; per-j distance via
// 64-lane butterfly; d_j parked in lane j; coalesced 28-float store; block
// loss reduce -> 1 atomic/block.
// ---------------------------------------------------------------------------
__global__ __launch_bounds__(256, 4)
void finalize(const float* __restrict__ tT, const float* __restrict__ r_acc,
              const float* __restrict__ creps, const float* __restrict__ labels,
              float* __restrict__ loss_acc, float* __restrict__ out) {
  __shared__ __align__(16) float cr[28 * 64];
  __shared__ float wsum[4];
  const int tid = threadIdx.x, w = tid >> 6, lane = tid & 63;
  for (int i = tid; i < 28 * 64; i += 256) cr[i] = creps[i];
  __syncthreads();

  const int q = blockIdx.x * 4 + w;
  float tval = 0.f;
  if (lane < 28) tval = tT[(size_t)lane * 4096 + q];
  tval *= 1.0f / fmaxf(r_acc[q], 1e-12f);

  // echo[c] for c = lane
  float echo = 0.f;
#pragma unroll
  for (int j = 0; j < 28; j++)
    echo = fmaf(__shfl(tval, j, 64), cr[j * 64 + lane], echo);

  float dj = 0.f;
#pragma unroll
  for (int j = 0; j < 28; j++) {
    float df = echo - cr[j * 64 + lane];
    float d2 = df * df;
#pragma unroll
    for (int m = 1; m < 64; m <<= 1) d2 += __shfl_xor(d2, m, 64);
    if (lane == j) dj = sqrtf(d2);
  }

  float lsum = 0.f;
  if (lane < 28) {
    out[1 + (size_t)q * 28 + lane] = -dj;
    float y = labels[(size_t)q * 28 + lane];
    lsum = fmaf(y, dj, log1pf(expf(-dj)));  // BCEWithLogits(-d, y), d >= 0
  }
#pragma unroll
  for (int m = 1; m < 64; m <<= 1) lsum += __shfl_xor(lsum, m, 64);
  if (lane == 0) wsum[w] = lsum;
  __syncthreads();
  if (tid == 0) atomicAdd(loss_acc, wsum[0] + wsum[1] + wsum[2] + wsum[3]);
}

__global__ void write_loss(const float* __restrict__ loss_acc, float* __restrict__ out) {
  out[0] = loss_acc[0] * (1.0f / 114688.0f);
}

// ---------------------------------------------------------------------------
extern "C" void kernel_launch(void* const* d_in, const int* in_sizes, int n_in,
                              void* d_out, int out_size, void* d_ws, size_t ws_size,
                              hipStream_t stream) {
  // Resolve inputs BY ELEMENT COUNT (unique per input; permutation-proof).
  const float* features = nullptr;  // 4096*1024   = 4194304
  const float* labels   = nullptr;  // 4096*28     = 114688
  const float* ex_feat  = nullptr;  // 16384*1024  = 16777216
  const float* ex_cls   = nullptr;  // 16384*28    = 458752
  const float* g_w      = nullptr;  // 256*1024    = 262144
  const float* creps    = nullptr;  // 28*64       = 1792
  for (int i = 0; i < n_in; i++) {
    switch (in_sizes[i]) {
      case 4194304:  features = (const float*)d_in[i]; break;
      case 114688:   labels   = (const float*)d_in[i]; break;
      case 16777216: ex_feat  = (const float*)d_in[i]; break;
      case 458752:   ex_cls   = (const float*)d_in[i]; break;
      case 262144:   g_w      = (const float*)d_in[i]; break;
      case 1792:     creps    = (const float*)d_in[i]; break;
      default: break;
    }
  }
  float* out = (float*)d_out;  // f32: [loss(1)] ++ [neg_dists 4096*28]

  if (!features || !labels || !ex_feat || !ex_cls || !g_w || !creps ||
      ws_size < (16ull << 20)) {
    fill_sentinel<<<256, 256, 0, stream>>>(out, out_size);  // diagnostic
    return;
  }

  char* ws = (char*)d_ws;
  __bf16* f_n   = (__bf16*)(ws);                    // 2 MB   [4096][256]
  __bf16* ef_n  = (__bf16*)(ws + (2ull << 20));     // 8 MB   [16384][256]
  __bf16* vT    = (__bf16*)(ws + (10ull << 20));    // 1 MB   [32][16384]
  float*  tT    = (float*) (ws + (11ull << 20));    // 512 KB [32][4096]
  float*  r_acc = tT + 32 * 4096;                   // 16 KB
  float*  lossp = r_acc + 4096;                     // 4 B

  zero_f32<<<528, 256, 0, stream>>>(tT, 32 * 4096 + 4096 + 1);

  proj_l2norm<<<640, 256, 0, stream>>>(ex_feat, features, g_w, ef_n, f_n);
  build_vt<<<64, 256, 0, stream>>>(ex_cls, vT);
  fused_sim<<<512, 256, 0, stream>>>(f_n, ef_n, vT, tT, r_acc);
  finalize<<<1024, 256, 0, stream>>>(tT, r_acc, creps, labels, lossp, out);
  write_loss<<<1, 1, 0, stream>>>(lossp, out);
}